// Round 10
// baseline (519.448 us; speedup 1.0000x reference)
//
#include <hip/hip_runtime.h>
#include <hip/hip_bf16.h>
#include <math.h>

// ---------------------------------------------------------------------------
// NetNode: 3x (GraphConv -> TopKPooling -> readout) + FC/BN head + per-node dot
// B=256, N=512, E=2048/graph, F=128, EMB=64. k1=461, k2=415, k3=374.
// R10: back to R7 champion structure (separate gather_direct + 2-input conv).
//  - conv v5: W read straight from global (L2-resident), NO LDS, NO barriers.
//  - topk_csr_k: topk-sort + edge remap + CSR build fused (same grid shape
//    as topk alone; readout stays wide). mapping array deleted.
//  - x0 kept alive so final_k streams it contiguously.
// ---------------------------------------------------------------------------

#define TOTAL_NODES 131072   // B*N
#define NUM_GRAPHS  256
#define NODES_PER_G 512
#define E_TOTAL     524288   // B*E
#define EPG         2048     // edges per graph (slot capacity)
#define FDIM        128
#define EMBD        64

typedef __bf16 bf16x8 __attribute__((ext_vector_type(8)));
typedef float  f32x4  __attribute__((ext_vector_type(4)));

static __device__ __forceinline__ f32x4 mfma16(bf16x8 a, bf16x8 b, f32x4 c) {
  return __builtin_amdgcn_mfma_f32_16x16x32_bf16(a, b, c, 0, 0, 0);
}

static inline size_t align256(size_t x) { return (x + 255) & ~size_t(255); }

// ---------------- gather embeddings
__global__ __launch_bounds__(256) void gather_embed_k(
    const int* __restrict__ item_id, const int* __restrict__ cat_id,
    const float* __restrict__ emb_item, const float* __restrict__ emb_cat,
    float* __restrict__ x, int total)
{
  int i = blockIdx.x * 256 + threadIdx.x;
  int node = i >> 5, part = i & 31;
  if (node >= total) return;
  float4 v;
  if (part < 16) {
    v = *(const float4*)&emb_item[(size_t)item_id[node] * EMBD + part * 4];
  } else {
    v = *(const float4*)&emb_cat[(size_t)cat_id[node] * EMBD + (part - 16) * 4];
  }
  *(float4*)&x[(size_t)node * FDIM + part * 4] = v;
}

// ---------------- W pre-split: W[k][n] fp32 -> Wh/Wl[n][k] bf16 (hi/lo)
__global__ __launch_bounds__(256) void wprep_k(
    const float* __restrict__ w0, const float* __restrict__ w1,
    const float* __restrict__ w2, const float* __restrict__ w3,
    const float* __restrict__ w4, const float* __restrict__ w5,
    __bf16* __restrict__ wout)
{
  const float* ws[6] = {w0, w1, w2, w3, w4, w5};
  int mat = blockIdx.y;
  int idx = blockIdx.x * 256 + threadIdx.x;   // 0..16383
  int n = idx >> 7, k = idx & 127;
  float v = ws[mat][k * FDIM + n];
  __bf16 h = (__bf16)v;
  __bf16 l = (__bf16)(v - (float)h);
  __bf16* base = wout + (size_t)mat * 2 * 16384;
  base[idx] = h;
  base[16384 + idx] = l;
}

// ---------------- norms of p1,p2,p3 in one launch
__global__ __launch_bounds__(128) void pnorm3_k(
    const float* __restrict__ p1, const float* __restrict__ p2,
    const float* __restrict__ p3, float* __restrict__ nrm)
{
  __shared__ float ss[128];
  const float* ps[3] = {p1, p2, p3};
  int t = threadIdx.x;
  for (int m = 0; m < 3; ++m) {
    float v = ps[m][t];
    ss[t] = v * v;
    __syncthreads();
    for (int s = 64; s > 0; s >>= 1) {
      if (t < s) ss[t] += ss[t + s];
      __syncthreads();
    }
    if (t == 0) nrm[m] = sqrtf(ss[0]);
    __syncthreads();
  }
}

// ---------------- stage-1 CSR build: edges global->local, slots {global row, 1}
__global__ __launch_bounds__(512) void csr_build1_k(
    const int* __restrict__ src_in, const int* __restrict__ dst_in,
    int* __restrict__ src_out, int* __restrict__ dst_out,
    int2* __restrict__ slot_pack, int* __restrict__ counts, int* __restrict__ offs)
{
  __shared__ int hist[512];
  __shared__ int scn[512];
  __shared__ int cur[512];
  const int b = blockIdx.x, t = threadIdx.x;
  const int ebase = b * EPG;
  const int nbase = b * NODES_PER_G;
  hist[t] = 0;
  __syncthreads();
  int so[4], ld[4];
#pragma unroll
  for (int i = 0; i < 4; ++i) {
    int e = ebase + t + i * 512;
    int s = src_in[e] - nbase;
    int d = dst_in[e] - nbase;
    src_out[e] = s; dst_out[e] = d;
    so[i] = s; ld[i] = d;
    atomicAdd(&hist[d], 1);
  }
  __syncthreads();
  int v = hist[t];
  scn[t] = v;
  __syncthreads();
  for (int dd = 1; dd < 512; dd <<= 1) {
    int add = (t >= dd) ? scn[t - dd] : 0;
    __syncthreads();
    scn[t] += add;
    __syncthreads();
  }
  {
    int excl = scn[t] - v;
    counts[nbase + t] = v;
    offs[nbase + t] = ebase + excl;
    cur[t] = excl;
  }
  __syncthreads();
#pragma unroll
  for (int i = 0; i < 4; ++i) {
    int pos = atomicAdd(&cur[ld[i]], 1);
    slot_pack[ebase + pos] = make_int2(nbase + so[i], __float_as_int(1.0f));
  }
}

// ---------------- direct register gather: agg[i] = sum gate_e * x[old_e]
__global__ __launch_bounds__(256) void gather_direct_k(
    const float* __restrict__ x, const int2* __restrict__ slot_pack,
    const int* __restrict__ off, const int* __restrict__ counts,
    float* __restrict__ agg, int M)
{
  int i = blockIdx.x * 256 + threadIdx.x;
  int node = i >> 5, lane = i & 31;
  if (node >= M) return;
  int deg = counts[node];
  int base = off[node];
  float4 a = make_float4(0.f, 0.f, 0.f, 0.f);
  for (int d = 0; d < deg; ++d) {
    int2 sp = slot_pack[base + d];
    float gt = __int_as_float(sp.y);
    float4 v = *(const float4*)&x[(size_t)sp.x * FDIM + lane * 4];
    a.x += gt * v.x; a.y += gt * v.y; a.z += gt * v.z; a.w += gt * v.w;
  }
  *(float4*)&agg[(size_t)node * FDIM + lane * 4] = a;
}

// ---------------- conv v5: C[M,128] = relu(Aroot@Wr + A2@Wn + b), bf16x3 MFMA
// Aroot row r = Asrc[sel[r]]*gates[r] (dense if sel==null). W bf16 hi/lo [n][k]
// read DIRECTLY from global (L2-resident, no LDS, no barriers). Fused score.
// In-place safe: C may alias A2 (blocks touch only their own 128 rows, all
// reads precede writes).
__global__ __launch_bounds__(256) void conv_mfma_k(
    const float* __restrict__ Asrc, const int* __restrict__ sel,
    const float* __restrict__ gates,
    const __bf16* __restrict__ Wr_hl,
    const float* __restrict__ A2,
    const __bf16* __restrict__ Wn_hl,
    const float* __restrict__ bias, const float* __restrict__ p,
    const float* __restrict__ nrm, float* __restrict__ C,
    float* __restrict__ score, int M)
{
  const int tid  = threadIdx.x;
  const int lane = tid & 63;
  const int w    = tid >> 6;
  const int row0 = blockIdx.x * 128;
  const int l15  = lane & 15;
  const int lg   = lane >> 4;

  f32x4 acc[2][8];
#pragma unroll
  for (int rf = 0; rf < 2; ++rf)
#pragma unroll
    for (int cf = 0; cf < 8; ++cf) acc[rf][cf] = (f32x4){0.f, 0.f, 0.f, 0.f};

  const int grow0 = row0 + w * 32 + l15;
  const int grow1 = grow0 + 16;

  for (int pass = 0; pass < 2; ++pass) {
    const float* __restrict__ A = pass ? A2 : Asrc;
    const __bf16* __restrict__ Whl = pass ? Wn_hl : Wr_hl;
    const bool use_sel = (pass == 0) && (sel != nullptr);
    int srow0 = use_sel ? sel[grow0] : grow0;
    int srow1 = use_sel ? sel[grow1] : grow1;
    float gt0 = use_sel ? gates[grow0] : 1.0f;
    float gt1 = use_sel ? gates[grow1] : 1.0f;

    for (int half = 0; half < 2; ++half) {
      const int k0 = half * 64;
      // A fragments: global -> reg, gate, hi/lo split
      bf16x8 ah[2][2], al[2][2];
#pragma unroll
      for (int rf = 0; rf < 2; ++rf) {
        int srow = rf ? srow1 : srow0;
        float gt = rf ? gt1 : gt0;
#pragma unroll
        for (int kc = 0; kc < 2; ++kc) {
          const float* ap = &A[(size_t)srow * FDIM + k0 + kc * 32 + lg * 8];
          float4 u0 = *(const float4*)ap;
          float4 u1 = *(const float4*)(ap + 4);
          float av[8] = {u0.x, u0.y, u0.z, u0.w, u1.x, u1.y, u1.z, u1.w};
#pragma unroll
          for (int j = 0; j < 8; ++j) {
            float vv = av[j] * gt;
            __bf16 h = (__bf16)vv;
            ah[rf][kc][j] = h;
            al[rf][kc][j] = (__bf16)(vv - (float)h);
          }
        }
      }
#pragma unroll
      for (int kc = 0; kc < 2; ++kc) {
        const int koff = k0 + kc * 32 + lg * 8;
#pragma unroll
        for (int cf = 0; cf < 8; ++cf) {
          const __bf16* bp = &Whl[(size_t)(cf * 16 + l15) * 128 + koff];
          bf16x8 bh = *(const bf16x8*)bp;
          bf16x8 bl = *(const bf16x8*)(bp + 16384);
          acc[0][cf] = mfma16(ah[0][kc], bh, acc[0][cf]);
          acc[0][cf] = mfma16(ah[0][kc], bl, acc[0][cf]);
          acc[0][cf] = mfma16(al[0][kc], bh, acc[0][cf]);
          acc[1][cf] = mfma16(ah[1][kc], bh, acc[1][cf]);
          acc[1][cf] = mfma16(ah[1][kc], bl, acc[1][cf]);
          acc[1][cf] = mfma16(al[1][kc], bh, acc[1][cf]);
        }
      }
    }
  }

  const float nv = nrm[0];
  float bv[8], pv[8];
#pragma unroll
  for (int cf = 0; cf < 8; ++cf) {
    int col = cf * 16 + l15;
    bv[cf] = bias[col];
    pv[cf] = p[col];
  }
#pragma unroll
  for (int rf = 0; rf < 2; ++rf) {
#pragma unroll
    for (int j = 0; j < 4; ++j) {
      int row = row0 + w * 32 + rf * 16 + lg * 4 + j;
      float* crow = &C[(size_t)row * FDIM];
      float rsv = 0.f;
#pragma unroll
      for (int cf = 0; cf < 8; ++cf) {
        float val = acc[rf][cf][j] + bv[cf];
        val = fmaxf(val, 0.f);
        crow[cf * 16 + l15] = val;
        rsv += val * pv[cf];
      }
      rsv += __shfl_xor(rsv, 1, 16);
      rsv += __shfl_xor(rsv, 2, 16);
      rsv += __shfl_xor(rsv, 4, 16);
      rsv += __shfl_xor(rsv, 8, 16);
      if (l15 == 0) score[row] = rsv / nv;
    }
  }
}

// ---------------- topk_csr_k: topk-sort + sel/gates + edge remap + CSR build
// One block (512 thr) per graph -- SAME grid shape as plain topk (readout is
// separate & wide, the R8 mistake is not repeated). src_e==null => last stage.
// Edges in LOCAL id space (-1 invalid), rewritten in place.
__global__ __launch_bounds__(512) void topk_csr_k(
    const float* __restrict__ score, int n_old, int k_new,
    int* __restrict__ sel, float* __restrict__ gates,
    int* __restrict__ src_e, int* __restrict__ dst_e,
    int2* __restrict__ slot_pack, int* __restrict__ counts,
    int* __restrict__ offs)
{
  __shared__ float sv[512];
  __shared__ int   si[512];
  __shared__ int   map_[512];
  __shared__ float gl[512];
  __shared__ int   hist[512];
  __shared__ int   scn[512];
  __shared__ int   cur[512];
  const int b = blockIdx.x, t = threadIdx.x;
  const int nbase = b * n_old;
  sv[t] = (t < n_old) ? -score[nbase + t] : 3.0e38f;
  si[t] = t;
  __syncthreads();
  for (int kk = 2; kk <= 512; kk <<= 1) {
    for (int j = kk >> 1; j > 0; j >>= 1) {
      int ixj = t ^ j;
      if (ixj > t) {
        bool up = ((t & kk) == 0);
        float a = sv[t], c = sv[ixj];
        if ((a > c) == up) {
          sv[t] = c; sv[ixj] = a;
          int tmp = si[t]; si[t] = si[ixj]; si[ixj] = tmp;
        }
      }
      __syncthreads();
    }
  }
  if (t < n_old) {
    int o = si[t];
    if (t < k_new) {
      float gt = tanhf(-sv[t]);
      sel[b * k_new + t] = nbase + o;
      gates[b * k_new + t] = gt;
      gl[t] = gt;
      map_[o] = t;
    } else {
      map_[o] = -1;
    }
  }
  __syncthreads();
  if (src_e) {
    hist[t] = 0;
    __syncthreads();
    const int ebase = b * EPG;
    int so[4], ls[4], ld[4];
#pragma unroll
    for (int i = 0; i < 4; ++i) {
      int e = ebase + t + i * 512;
      int s = src_e[e], d = dst_e[e];
      so[i] = s;
      int ns = (s >= 0) ? map_[s] : -1;
      int nd = (d >= 0) ? map_[d] : -1;
      if (ns < 0 || nd < 0) { ns = -1; nd = -1; }
      src_e[e] = ns; dst_e[e] = nd;
      ls[i] = ns; ld[i] = nd;
      if (nd >= 0) atomicAdd(&hist[nd], 1);
    }
    __syncthreads();
    int v = (t < k_new) ? hist[t] : 0;
    scn[t] = v;
    __syncthreads();
    for (int dd = 1; dd < 512; dd <<= 1) {
      int add = (t >= dd) ? scn[t - dd] : 0;
      __syncthreads();
      scn[t] += add;
      __syncthreads();
    }
    if (t < k_new) {
      int excl = scn[t] - v;
      counts[b * k_new + t] = v;
      offs[b * k_new + t] = ebase + excl;
      cur[t] = excl;
    }
    __syncthreads();
#pragma unroll
    for (int i = 0; i < 4; ++i) {
      if (ld[i] >= 0) {
        int pos = atomicAdd(&cur[ld[i]], 1);
        slot_pack[ebase + pos] = make_int2(nbase + so[i], __float_as_int(gl[ls[i]]));
      }
    }
  }
}

// ---------------- readout over pooled rows (wide grid, no materialization)
__global__ __launch_bounds__(256) void readout_k(
    const float* __restrict__ x, const int* __restrict__ sel,
    const float* __restrict__ gates, float* __restrict__ g, int k)
{
  __shared__ float lmx[32 * 36];
  __shared__ float lsm[32 * 36];
  const int b = blockIdx.x, ch = blockIdx.y;
  const int c0 = ch * 32;
  const int tid = threadIdx.x;
  const int lane = tid & 7;
  const int slot = tid >> 3;
  float4 mx = make_float4(-3.0e38f, -3.0e38f, -3.0e38f, -3.0e38f);
  float4 sm = make_float4(0.f, 0.f, 0.f, 0.f);
  for (int n = slot; n < k; n += 32) {
    int node = b * k + n;
    int old = sel[node];
    float gate = gates[node];
    float4 v = *(const float4*)&x[(size_t)old * FDIM + c0 + lane * 4];
    v.x *= gate; v.y *= gate; v.z *= gate; v.w *= gate;
    mx.x = fmaxf(mx.x, v.x); mx.y = fmaxf(mx.y, v.y);
    mx.z = fmaxf(mx.z, v.z); mx.w = fmaxf(mx.w, v.w);
    sm.x += v.x; sm.y += v.y; sm.z += v.z; sm.w += v.w;
  }
  float* pm = &lmx[slot * 36 + lane * 4];
  float* ps = &lsm[slot * 36 + lane * 4];
  pm[0] = mx.x; pm[1] = mx.y; pm[2] = mx.z; pm[3] = mx.w;
  ps[0] = sm.x; ps[1] = sm.y; ps[2] = sm.z; ps[3] = sm.w;
  __syncthreads();
  for (int s = 16; s > 0; s >>= 1) {
    if (slot < s) {
#pragma unroll
      for (int j = 0; j < 4; ++j) {
        int a = slot * 36 + lane * 4 + j;
        int bb = (slot + s) * 36 + lane * 4 + j;
        lmx[a] = fmaxf(lmx[a], lmx[bb]);
        lsm[a] += lsm[bb];
      }
    }
    __syncthreads();
  }
  if (slot == 0) {
    float inv_k = 1.f / (float)k;
#pragma unroll
    for (int j = 0; j < 4; ++j) {
      int c = c0 + lane * 4 + j;
      g[b * 256 + c]       += lmx[lane * 4 + j];
      g[b * 256 + 128 + c] += lsm[lane * 4 + j] * inv_k;
    }
  }
}

// ---------------- head1: h1 = relu(bn1(g @ fc1_W + b1)); 16 blocks x 8 cols
__global__ __launch_bounds__(256) void head1_k(
    const float* __restrict__ g, const float* __restrict__ W,
    const float* __restrict__ bias, const float* __restrict__ gamma,
    const float* __restrict__ beta, float* __restrict__ h1)
{
  __shared__ float wsl[256 * 8];
  __shared__ float rsum[256 * 9];
  __shared__ float rsq[256 * 9];
  const int c0 = blockIdx.x * 8;
  const int t = threadIdx.x;
#pragma unroll
  for (int j = 0; j < 8; ++j) wsl[t * 8 + j] = W[t * 128 + c0 + j];
  __syncthreads();
  float acc[8] = {0.f, 0.f, 0.f, 0.f, 0.f, 0.f, 0.f, 0.f};
  const float* grow = &g[t * 256];
#pragma unroll
  for (int k = 0; k < 256; k += 4) {
    float4 gv = *(const float4*)&grow[k];
#pragma unroll
    for (int j = 0; j < 8; ++j) {
      acc[j] += gv.x * wsl[(k + 0) * 8 + j] + gv.y * wsl[(k + 1) * 8 + j]
              + gv.z * wsl[(k + 2) * 8 + j] + gv.w * wsl[(k + 3) * 8 + j];
    }
  }
#pragma unroll
  for (int j = 0; j < 8; ++j) {
    acc[j] += bias[c0 + j];
    rsum[t * 9 + j] = acc[j];
    rsq[t * 9 + j] = acc[j] * acc[j];
  }
  __syncthreads();
  for (int s = 128; s > 0; s >>= 1) {
    if (t < s) {
#pragma unroll
      for (int j = 0; j < 8; ++j) {
        rsum[t * 9 + j] += rsum[(t + s) * 9 + j];
        rsq[t * 9 + j]  += rsq[(t + s) * 9 + j];
      }
    }
    __syncthreads();
  }
#pragma unroll
  for (int j = 0; j < 8; ++j) {
    float m = rsum[j] * (1.f / 256.f);
    float var = rsq[j] * (1.f / 256.f) - m * m;
    float o = gamma[c0 + j] * (acc[j] - m) * rsqrtf(var + 1e-5f) + beta[c0 + j];
    h1[t * 128 + c0 + j] = fmaxf(o, 0.f);
  }
}

// ---------------- head2: h2 = relu(bn2(h1 @ fc2_W + b2)); 8 blocks x 8 cols
__global__ __launch_bounds__(256) void head2_k(
    const float* __restrict__ h1, const float* __restrict__ W,
    const float* __restrict__ bias, const float* __restrict__ gamma,
    const float* __restrict__ beta, float* __restrict__ h2)
{
  __shared__ float wsl[128 * 8];
  __shared__ float rsum[256 * 9];
  __shared__ float rsq[256 * 9];
  const int c0 = blockIdx.x * 8;
  const int t = threadIdx.x;
  if (t < 128) {
#pragma unroll
    for (int j = 0; j < 8; ++j) wsl[t * 8 + j] = W[t * 64 + c0 + j];
  }
  __syncthreads();
  float acc[8] = {0.f, 0.f, 0.f, 0.f, 0.f, 0.f, 0.f, 0.f};
  const float* hrow = &h1[t * 128];
#pragma unroll
  for (int k = 0; k < 128; k += 4) {
    float4 gv = *(const float4*)&hrow[k];
#pragma unroll
    for (int j = 0; j < 8; ++j) {
      acc[j] += gv.x * wsl[(k + 0) * 8 + j] + gv.y * wsl[(k + 1) * 8 + j]
              + gv.z * wsl[(k + 2) * 8 + j] + gv.w * wsl[(k + 3) * 8 + j];
    }
  }
#pragma unroll
  for (int j = 0; j < 8; ++j) {
    acc[j] += bias[c0 + j];
    rsum[t * 9 + j] = acc[j];
    rsq[t * 9 + j] = acc[j] * acc[j];
  }
  __syncthreads();
  for (int s = 128; s > 0; s >>= 1) {
    if (t < s) {
#pragma unroll
      for (int j = 0; j < 8; ++j) {
        rsum[t * 9 + j] += rsum[(t + s) * 9 + j];
        rsq[t * 9 + j]  += rsq[(t + s) * 9 + j];
      }
    }
    __syncthreads();
  }
#pragma unroll
  for (int j = 0; j < 8; ++j) {
    float m = rsum[j] * (1.f / 256.f);
    float var = rsq[j] * (1.f / 256.f) - m * m;
    float o = gamma[c0 + j] * (acc[j] - m) * rsqrtf(var + 1e-5f) + beta[c0 + j];
    h2[t * 64 + c0 + j] = fmaxf(o, 0.f);
  }
}

// ---------------- out[nid] = sigmoid(dot(x0[nid][0:64], h2[graph]))
__global__ __launch_bounds__(256) void final_k(
    const float* __restrict__ x0, const float* __restrict__ g2,
    float* __restrict__ out, int total)
{
  int nid = blockIdx.x * 256 + threadIdx.x;
  if (nid >= total) return;
  int b = nid >> 9;
  const float* e = &x0[(size_t)nid * FDIM];   // first 64 cols = emb_item row
  const float* gg = &g2[(size_t)b * 64];
  float s = 0.f;
#pragma unroll
  for (int j = 0; j < 64; j += 4) {
    float4 a = *(const float4*)&e[j];
    float4 c = *(const float4*)&gg[j];
    s += a.x * c.x + a.y * c.y + a.z * c.z + a.w * c.w;
  }
  out[nid] = 1.f / (1.f + expf(-s));
}

// ---------------------------------------------------------------------------
extern "C" void kernel_launch(void* const* d_in, const int* in_sizes, int n_in,
                              void* d_out, int out_size, void* d_ws, size_t ws_size,
                              hipStream_t stream)
{
  const int*   item_id  = (const int*)  d_in[0];
  const int*   cat_id   = (const int*)  d_in[1];
  const int*   src_in   = (const int*)  d_in[2];
  const int*   dst_in   = (const int*)  d_in[3];
  const float* emb_item = (const float*)d_in[4];
  const float* emb_cat  = (const float*)d_in[5];
  const float* W1r = (const float*)d_in[6];
  const float* W1n = (const float*)d_in[7];
  const float* b1  = (const float*)d_in[8];
  const float* p1  = (const float*)d_in[9];
  const float* W2r = (const float*)d_in[10];
  const float* W2n = (const float*)d_in[11];
  const float* b2  = (const float*)d_in[12];
  const float* p2  = (const float*)d_in[13];
  const float* W3r = (const float*)d_in[14];
  const float* W3n = (const float*)d_in[15];
  const float* b3  = (const float*)d_in[16];
  const float* p3  = (const float*)d_in[17];
  const float* fc1_W = (const float*)d_in[18];
  const float* fc1_b = (const float*)d_in[19];
  const float* bn1_g = (const float*)d_in[20];
  const float* bn1_b = (const float*)d_in[21];
  const float* fc2_W = (const float*)d_in[22];
  const float* fc2_b = (const float*)d_in[23];
  const float* bn2_g = (const float*)d_in[24];
  const float* bn2_b = (const float*)d_in[25];
  float* out = (float*)d_out;

  const int TN = TOTAL_NODES;
  const int E  = E_TOTAL;
  const int k1 = 461, k2 = 415, k3 = 374;
  const int M1 = TN;              // 131072
  const int M2 = NUM_GRAPHS * k1; // 118016
  const int M3 = NUM_GRAPHS * k2; // 106240

  char* ws = (char*)d_ws;
  size_t off = 0;
  auto carve = [&](size_t bytes) { char* p = ws + off; off += align256(bytes); return p; };
  float*  bufA   = (float*) carve((size_t)TN * FDIM * 4);  // x0 (persists)
  float*  bufB   = (float*) carve((size_t)TN * FDIM * 4);  // agg1/x1, agg3/x3
  float*  bufC   = (float*) carve((size_t)TN * FDIM * 4);  // agg2/x2
  float*  score  = (float*) carve((size_t)TN * 4);
  int*    sel    = (int*)   carve((size_t)TN * 4);
  float*  gates  = (float*) carve((size_t)TN * 4);
  int*    srcw   = (int*)   carve((size_t)E * 4);
  int*    dstw   = (int*)   carve((size_t)E * 4);
  int*    counts = (int*)   carve((size_t)TN * 4);
  int*    offs   = (int*)   carve((size_t)TN * 4);
  int2*   slotp  = (int2*)  carve((size_t)E * 8);
  __bf16* wbuf   = (__bf16*)carve(6 * 2 * 16384 * 2);
  float*  g      = (float*) carve(256 * 256 * 4);
  float*  h1     = (float*) carve(256 * 128 * 4);
  float*  h2     = (float*) carve(256 * 64 * 4);
  float*  nrm    = (float*) carve(256);
  if (off > ws_size) return;

  dim3 b256(256);
  auto blocks = [](long long work, int bs) { return dim3((unsigned)((work + bs - 1) / bs)); };

  const __bf16* W1r_hl = wbuf + 0 * 2 * 16384;
  const __bf16* W1n_hl = wbuf + 1 * 2 * 16384;
  const __bf16* W2r_hl = wbuf + 2 * 2 * 16384;
  const __bf16* W2n_hl = wbuf + 3 * 2 * 16384;
  const __bf16* W3r_hl = wbuf + 4 * 2 * 16384;
  const __bf16* W3n_hl = wbuf + 5 * 2 * 16384;

  hipMemsetAsync(g, 0, 256 * 256 * 4, stream);
  wprep_k<<<dim3(64, 6), b256, 0, stream>>>(W1r, W1n, W2r, W2n, W3r, W3n, wbuf);
  pnorm3_k<<<dim3(1), dim3(128), 0, stream>>>(p1, p2, p3, nrm);
  gather_embed_k<<<blocks((long long)TN * 32, 256), b256, 0, stream>>>(
      item_id, cat_id, emb_item, emb_cat, bufA, TN);

  // ================= stage 1 (x0 = bufA dense) =================
  csr_build1_k<<<dim3(NUM_GRAPHS), dim3(512), 0, stream>>>(
      src_in, dst_in, srcw, dstw, slotp, counts, offs);
  gather_direct_k<<<blocks((long long)M1 * 32, 256), b256, 0, stream>>>(
      bufA, slotp, offs, counts, bufB, M1);
  conv_mfma_k<<<dim3(M1 / 128), b256, 0, stream>>>(
      bufA, nullptr, nullptr, W1r_hl, bufB, W1n_hl, b1, p1, nrm + 0, bufB, score, M1);
  topk_csr_k<<<dim3(NUM_GRAPHS), dim3(512), 0, stream>>>(
      score, NODES_PER_G, k1, sel, gates, srcw, dstw, slotp, counts, offs);
  readout_k<<<dim3(NUM_GRAPHS, 4), b256, 0, stream>>>(bufB, sel, gates, g, k1);

  // ================= stage 2 (x1 = bufB via sel/gates) =================
  gather_direct_k<<<blocks((long long)M2 * 32, 256), b256, 0, stream>>>(
      bufB, slotp, offs, counts, bufC, M2);
  conv_mfma_k<<<dim3(M2 / 128), b256, 0, stream>>>(
      bufB, sel, gates, W2r_hl, bufC, W2n_hl, b2, p2, nrm + 1, bufC, score, M2);
  topk_csr_k<<<dim3(NUM_GRAPHS), dim3(512), 0, stream>>>(
      score, k1, k2, sel, gates, srcw, dstw, slotp, counts, offs);
  readout_k<<<dim3(NUM_GRAPHS, 4), b256, 0, stream>>>(bufC, sel, gates, g, k2);

  // ================= stage 3 (x2 = bufC via sel/gates) =================
  gather_direct_k<<<blocks((long long)M3 * 32, 256), b256, 0, stream>>>(
      bufC, slotp, offs, counts, bufB, M3);
  conv_mfma_k<<<dim3(M3 / 128), b256, 0, stream>>>(
      bufC, sel, gates, W3r_hl, bufB, W3n_hl, b3, p3, nrm + 2, bufB, score, M3);
  topk_csr_k<<<dim3(NUM_GRAPHS), dim3(512), 0, stream>>>(
      score, k2, k3, sel, gates, nullptr, nullptr, nullptr, nullptr, nullptr);
  readout_k<<<dim3(NUM_GRAPHS, 4), b256, 0, stream>>>(bufB, sel, gates, g, k3);

  // ================= head (fused fc+bn+relu) =================
  head1_k<<<dim3(16), b256, 0, stream>>>(g, fc1_W, fc1_b, bn1_g, bn1_b, h1);
  head2_k<<<dim3(8), b256, 0, stream>>>(h1, fc2_W, fc2_b, bn2_g, bn2_b, h2);

  final_k<<<blocks(TN, 256), b256, 0, stream>>>(bufA, h2, out, TN);
}

// Round 11
// 409.919 us; speedup vs baseline: 1.2672x; 1.2672x over previous
//
#include <hip/hip_runtime.h>
#include <hip/hip_bf16.h>
#include <math.h>

// ---------------------------------------------------------------------------
// NetNode: 3x (GraphConv -> TopKPooling -> readout) + FC/BN head + per-node dot
// B=256, N=512, E=2048/graph, F=128, EMB=64. k1=461, k2=415, k3=374.
// R11: R10 minus the conv regression -- conv restored to the proven R5/R7
//     body (W hi/lo staged per-half in LDS; global-W re-reads were 2x slower).
//     Keeps: fused topk_csr_k, no mapping array, x0 alive for final_k.
// ---------------------------------------------------------------------------

#define TOTAL_NODES 131072   // B*N
#define NUM_GRAPHS  256
#define NODES_PER_G 512
#define E_TOTAL     524288   // B*E
#define EPG         2048     // edges per graph (slot capacity)
#define FDIM        128
#define EMBD        64

typedef __bf16 bf16x8 __attribute__((ext_vector_type(8)));
typedef float  f32x4  __attribute__((ext_vector_type(4)));

static __device__ __forceinline__ f32x4 mfma16(bf16x8 a, bf16x8 b, f32x4 c) {
  return __builtin_amdgcn_mfma_f32_16x16x32_bf16(a, b, c, 0, 0, 0);
}

static inline size_t align256(size_t x) { return (x + 255) & ~size_t(255); }

// ---------------- gather embeddings
__global__ __launch_bounds__(256) void gather_embed_k(
    const int* __restrict__ item_id, const int* __restrict__ cat_id,
    const float* __restrict__ emb_item, const float* __restrict__ emb_cat,
    float* __restrict__ x, int total)
{
  int i = blockIdx.x * 256 + threadIdx.x;
  int node = i >> 5, part = i & 31;
  if (node >= total) return;
  float4 v;
  if (part < 16) {
    v = *(const float4*)&emb_item[(size_t)item_id[node] * EMBD + part * 4];
  } else {
    v = *(const float4*)&emb_cat[(size_t)cat_id[node] * EMBD + (part - 16) * 4];
  }
  *(float4*)&x[(size_t)node * FDIM + part * 4] = v;
}

// ---------------- W pre-split: W[k][n] fp32 -> Wh/Wl[n][k] bf16 (hi/lo)
__global__ __launch_bounds__(256) void wprep_k(
    const float* __restrict__ w0, const float* __restrict__ w1,
    const float* __restrict__ w2, const float* __restrict__ w3,
    const float* __restrict__ w4, const float* __restrict__ w5,
    __bf16* __restrict__ wout)
{
  const float* ws[6] = {w0, w1, w2, w3, w4, w5};
  int mat = blockIdx.y;
  int idx = blockIdx.x * 256 + threadIdx.x;   // 0..16383
  int n = idx >> 7, k = idx & 127;
  float v = ws[mat][k * FDIM + n];
  __bf16 h = (__bf16)v;
  __bf16 l = (__bf16)(v - (float)h);
  __bf16* base = wout + (size_t)mat * 2 * 16384;
  base[idx] = h;
  base[16384 + idx] = l;
}

// ---------------- norms of p1,p2,p3 in one launch
__global__ __launch_bounds__(128) void pnorm3_k(
    const float* __restrict__ p1, const float* __restrict__ p2,
    const float* __restrict__ p3, float* __restrict__ nrm)
{
  __shared__ float ss[128];
  const float* ps[3] = {p1, p2, p3};
  int t = threadIdx.x;
  for (int m = 0; m < 3; ++m) {
    float v = ps[m][t];
    ss[t] = v * v;
    __syncthreads();
    for (int s = 64; s > 0; s >>= 1) {
      if (t < s) ss[t] += ss[t + s];
      __syncthreads();
    }
    if (t == 0) nrm[m] = sqrtf(ss[0]);
    __syncthreads();
  }
}

// ---------------- stage-1 CSR build: edges global->local, slots {global row, 1}
__global__ __launch_bounds__(512) void csr_build1_k(
    const int* __restrict__ src_in, const int* __restrict__ dst_in,
    int* __restrict__ src_out, int* __restrict__ dst_out,
    int2* __restrict__ slot_pack, int* __restrict__ counts, int* __restrict__ offs)
{
  __shared__ int hist[512];
  __shared__ int scn[512];
  __shared__ int cur[512];
  const int b = blockIdx.x, t = threadIdx.x;
  const int ebase = b * EPG;
  const int nbase = b * NODES_PER_G;
  hist[t] = 0;
  __syncthreads();
  int so[4], ld[4];
#pragma unroll
  for (int i = 0; i < 4; ++i) {
    int e = ebase + t + i * 512;
    int s = src_in[e] - nbase;
    int d = dst_in[e] - nbase;
    src_out[e] = s; dst_out[e] = d;
    so[i] = s; ld[i] = d;
    atomicAdd(&hist[d], 1);
  }
  __syncthreads();
  int v = hist[t];
  scn[t] = v;
  __syncthreads();
  for (int dd = 1; dd < 512; dd <<= 1) {
    int add = (t >= dd) ? scn[t - dd] : 0;
    __syncthreads();
    scn[t] += add;
    __syncthreads();
  }
  {
    int excl = scn[t] - v;
    counts[nbase + t] = v;
    offs[nbase + t] = ebase + excl;
    cur[t] = excl;
  }
  __syncthreads();
#pragma unroll
  for (int i = 0; i < 4; ++i) {
    int pos = atomicAdd(&cur[ld[i]], 1);
    slot_pack[ebase + pos] = make_int2(nbase + so[i], __float_as_int(1.0f));
  }
}

// ---------------- direct register gather: agg[i] = sum gate_e * x[old_e]
__global__ __launch_bounds__(256) void gather_direct_k(
    const float* __restrict__ x, const int2* __restrict__ slot_pack,
    const int* __restrict__ off, const int* __restrict__ counts,
    float* __restrict__ agg, int M)
{
  int i = blockIdx.x * 256 + threadIdx.x;
  int node = i >> 5, lane = i & 31;
  if (node >= M) return;
  int deg = counts[node];
  int base = off[node];
  float4 a = make_float4(0.f, 0.f, 0.f, 0.f);
  for (int d = 0; d < deg; ++d) {
    int2 sp = slot_pack[base + d];
    float gt = __int_as_float(sp.y);
    float4 v = *(const float4*)&x[(size_t)sp.x * FDIM + lane * 4];
    a.x += gt * v.x; a.y += gt * v.y; a.z += gt * v.z; a.w += gt * v.w;
  }
  *(float4*)&agg[(size_t)node * FDIM + lane * 4] = a;
}

// ---------------- conv (R5/R7 proven body): C = relu(Aroot@Wr + A2@Wn + b)
// bf16x3 MFMA. Aroot row r = Asrc[sel[r]]*gates[r] (dense if sel==null).
// W pre-split bf16 hi/lo [n][k], staged per-half in LDS. A loaded global->reg.
// Fused score epilogue. In-place safe: C may alias A2 (blocks touch only
// their own 128 rows; all reads precede writes).
__global__ __launch_bounds__(256) void conv_mfma_k(
    const float* __restrict__ Asrc, const int* __restrict__ sel,
    const float* __restrict__ gates,
    const __bf16* __restrict__ W1hl,
    const float* __restrict__ A2,
    const __bf16* __restrict__ W2hl,
    const float* __restrict__ bias, const float* __restrict__ p,
    const float* __restrict__ nrm, float* __restrict__ C,
    float* __restrict__ score, int M)
{
  __shared__ __bf16 Wh[128 * 72];   // 18 KB
  __shared__ __bf16 Wl[128 * 72];   // 18 KB

  const int tid  = threadIdx.x;
  const int lane = tid & 63;
  const int w    = tid >> 6;
  const int row0 = blockIdx.x * 128;
  const int l15  = lane & 15;
  const int lg   = lane >> 4;

  f32x4 acc[2][8];
#pragma unroll
  for (int rf = 0; rf < 2; ++rf)
#pragma unroll
    for (int cf = 0; cf < 8; ++cf) acc[rf][cf] = (f32x4){0.f, 0.f, 0.f, 0.f};

  const int grow0 = row0 + w * 32 + l15;
  const int grow1 = grow0 + 16;

  for (int pass = 0; pass < 2; ++pass) {
    const float* __restrict__ A = pass ? A2 : Asrc;
    const __bf16* __restrict__ Whl = pass ? W2hl : W1hl;
    const bool use_sel = (pass == 0) && (sel != nullptr);
    int srow0 = use_sel ? sel[grow0] : grow0;
    int srow1 = use_sel ? sel[grow1] : grow1;
    float gt0 = use_sel ? gates[grow0] : 1.0f;
    float gt1 = use_sel ? gates[grow1] : 1.0f;

    for (int half = 0; half < 2; ++half) {
      const int k0 = half * 64;
      __syncthreads();   // protect prior half's LDS reads
      // stage W-half: 128 cols x 64 k, hi+lo
      for (int v = tid; v < 1024; v += 256) {
        int c = v >> 3, chn = (v & 7) * 8;
        *(bf16x8*)&Wh[c * 72 + chn] = *(const bf16x8*)&Whl[c * 128 + k0 + chn];
        *(bf16x8*)&Wl[c * 72 + chn] = *(const bf16x8*)&Whl[16384 + c * 128 + k0 + chn];
      }
      __syncthreads();

      // A fragments: global -> reg, gate, hi/lo split
      bf16x8 ah[2][2], al[2][2];
#pragma unroll
      for (int rf = 0; rf < 2; ++rf) {
        int srow = rf ? srow1 : srow0;
        float gt = rf ? gt1 : gt0;
#pragma unroll
        for (int kc = 0; kc < 2; ++kc) {
          const float* ap = &A[(size_t)srow * FDIM + k0 + kc * 32 + lg * 8];
          float4 u0 = *(const float4*)ap;
          float4 u1 = *(const float4*)(ap + 4);
          float av[8] = {u0.x, u0.y, u0.z, u0.w, u1.x, u1.y, u1.z, u1.w};
#pragma unroll
          for (int j = 0; j < 8; ++j) {
            float vv = av[j] * gt;
            __bf16 h = (__bf16)vv;
            ah[rf][kc][j] = h;
            al[rf][kc][j] = (__bf16)(vv - (float)h);
          }
        }
      }
#pragma unroll
      for (int kc = 0; kc < 2; ++kc) {
        const int koff = kc * 32 + lg * 8;
#pragma unroll
        for (int cf = 0; cf < 8; ++cf) {
          const int bo = (cf * 16 + l15) * 72 + koff;
          bf16x8 bh = *(const bf16x8*)&Wh[bo];
          bf16x8 bl = *(const bf16x8*)&Wl[bo];
          acc[0][cf] = mfma16(ah[0][kc], bh, acc[0][cf]);
          acc[0][cf] = mfma16(ah[0][kc], bl, acc[0][cf]);
          acc[0][cf] = mfma16(al[0][kc], bh, acc[0][cf]);
          acc[1][cf] = mfma16(ah[1][kc], bh, acc[1][cf]);
          acc[1][cf] = mfma16(ah[1][kc], bl, acc[1][cf]);
          acc[1][cf] = mfma16(al[1][kc], bh, acc[1][cf]);
        }
      }
    }
  }

  const float nv = nrm[0];
  float bv[8], pv[8];
#pragma unroll
  for (int cf = 0; cf < 8; ++cf) {
    int col = cf * 16 + l15;
    bv[cf] = bias[col];
    pv[cf] = p[col];
  }
#pragma unroll
  for (int rf = 0; rf < 2; ++rf) {
#pragma unroll
    for (int j = 0; j < 4; ++j) {
      int row = row0 + w * 32 + rf * 16 + lg * 4 + j;
      float* crow = &C[(size_t)row * FDIM];
      float rsv = 0.f;
#pragma unroll
      for (int cf = 0; cf < 8; ++cf) {
        float val = acc[rf][cf][j] + bv[cf];
        val = fmaxf(val, 0.f);
        crow[cf * 16 + l15] = val;
        rsv += val * pv[cf];
      }
      rsv += __shfl_xor(rsv, 1, 16);
      rsv += __shfl_xor(rsv, 2, 16);
      rsv += __shfl_xor(rsv, 4, 16);
      rsv += __shfl_xor(rsv, 8, 16);
      if (l15 == 0) score[row] = rsv / nv;
    }
  }
}

// ---------------- topk_csr_k: topk-sort + sel/gates + edge remap + CSR build
// One block (512 thr) per graph. src_e==null => last stage (no CSR).
// Edges in LOCAL id space (-1 invalid), rewritten in place.
__global__ __launch_bounds__(512) void topk_csr_k(
    const float* __restrict__ score, int n_old, int k_new,
    int* __restrict__ sel, float* __restrict__ gates,
    int* __restrict__ src_e, int* __restrict__ dst_e,
    int2* __restrict__ slot_pack, int* __restrict__ counts,
    int* __restrict__ offs)
{
  __shared__ float sv[512];
  __shared__ int   si[512];
  __shared__ int   map_[512];
  __shared__ float gl[512];
  __shared__ int   hist[512];
  __shared__ int   scn[512];
  __shared__ int   cur[512];
  const int b = blockIdx.x, t = threadIdx.x;
  const int nbase = b * n_old;
  sv[t] = (t < n_old) ? -score[nbase + t] : 3.0e38f;
  si[t] = t;
  __syncthreads();
  for (int kk = 2; kk <= 512; kk <<= 1) {
    for (int j = kk >> 1; j > 0; j >>= 1) {
      int ixj = t ^ j;
      if (ixj > t) {
        bool up = ((t & kk) == 0);
        float a = sv[t], c = sv[ixj];
        if ((a > c) == up) {
          sv[t] = c; sv[ixj] = a;
          int tmp = si[t]; si[t] = si[ixj]; si[ixj] = tmp;
        }
      }
      __syncthreads();
    }
  }
  if (t < n_old) {
    int o = si[t];
    if (t < k_new) {
      float gt = tanhf(-sv[t]);
      sel[b * k_new + t] = nbase + o;
      gates[b * k_new + t] = gt;
      gl[t] = gt;
      map_[o] = t;
    } else {
      map_[o] = -1;
    }
  }
  __syncthreads();
  if (src_e) {
    hist[t] = 0;
    __syncthreads();
    const int ebase = b * EPG;
    int so[4], ls[4], ld[4];
#pragma unroll
    for (int i = 0; i < 4; ++i) {
      int e = ebase + t + i * 512;
      int s = src_e[e], d = dst_e[e];
      so[i] = s;
      int ns = (s >= 0) ? map_[s] : -1;
      int nd = (d >= 0) ? map_[d] : -1;
      if (ns < 0 || nd < 0) { ns = -1; nd = -1; }
      src_e[e] = ns; dst_e[e] = nd;
      ls[i] = ns; ld[i] = nd;
      if (nd >= 0) atomicAdd(&hist[nd], 1);
    }
    __syncthreads();
    int v = (t < k_new) ? hist[t] : 0;
    scn[t] = v;
    __syncthreads();
    for (int dd = 1; dd < 512; dd <<= 1) {
      int add = (t >= dd) ? scn[t - dd] : 0;
      __syncthreads();
      scn[t] += add;
      __syncthreads();
    }
    if (t < k_new) {
      int excl = scn[t] - v;
      counts[b * k_new + t] = v;
      offs[b * k_new + t] = ebase + excl;
      cur[t] = excl;
    }
    __syncthreads();
#pragma unroll
    for (int i = 0; i < 4; ++i) {
      if (ld[i] >= 0) {
        int pos = atomicAdd(&cur[ld[i]], 1);
        slot_pack[ebase + pos] = make_int2(nbase + so[i], __float_as_int(gl[ls[i]]));
      }
    }
  }
}

// ---------------- readout over pooled rows (wide grid, no materialization)
__global__ __launch_bounds__(256) void readout_k(
    const float* __restrict__ x, const int* __restrict__ sel,
    const float* __restrict__ gates, float* __restrict__ g, int k)
{
  __shared__ float lmx[32 * 36];
  __shared__ float lsm[32 * 36];
  const int b = blockIdx.x, ch = blockIdx.y;
  const int c0 = ch * 32;
  const int tid = threadIdx.x;
  const int lane = tid & 7;
  const int slot = tid >> 3;
  float4 mx = make_float4(-3.0e38f, -3.0e38f, -3.0e38f, -3.0e38f);
  float4 sm = make_float4(0.f, 0.f, 0.f, 0.f);
  for (int n = slot; n < k; n += 32) {
    int node = b * k + n;
    int old = sel[node];
    float gate = gates[node];
    float4 v = *(const float4*)&x[(size_t)old * FDIM + c0 + lane * 4];
    v.x *= gate; v.y *= gate; v.z *= gate; v.w *= gate;
    mx.x = fmaxf(mx.x, v.x); mx.y = fmaxf(mx.y, v.y);
    mx.z = fmaxf(mx.z, v.z); mx.w = fmaxf(mx.w, v.w);
    sm.x += v.x; sm.y += v.y; sm.z += v.z; sm.w += v.w;
  }
  float* pm = &lmx[slot * 36 + lane * 4];
  float* ps = &lsm[slot * 36 + lane * 4];
  pm[0] = mx.x; pm[1] = mx.y; pm[2] = mx.z; pm[3] = mx.w;
  ps[0] = sm.x; ps[1] = sm.y; ps[2] = sm.z; ps[3] = sm.w;
  __syncthreads();
  for (int s = 16; s > 0; s >>= 1) {
    if (slot < s) {
#pragma unroll
      for (int j = 0; j < 4; ++j) {
        int a = slot * 36 + lane * 4 + j;
        int bb = (slot + s) * 36 + lane * 4 + j;
        lmx[a] = fmaxf(lmx[a], lmx[bb]);
        lsm[a] += lsm[bb];
      }
    }
    __syncthreads();
  }
  if (slot == 0) {
    float inv_k = 1.f / (float)k;
#pragma unroll
    for (int j = 0; j < 4; ++j) {
      int c = c0 + lane * 4 + j;
      g[b * 256 + c]       += lmx[lane * 4 + j];
      g[b * 256 + 128 + c] += lsm[lane * 4 + j] * inv_k;
    }
  }
}

// ---------------- head1: h1 = relu(bn1(g @ fc1_W + b1)); 16 blocks x 8 cols
__global__ __launch_bounds__(256) void head1_k(
    const float* __restrict__ g, const float* __restrict__ W,
    const float* __restrict__ bias, const float* __restrict__ gamma,
    const float* __restrict__ beta, float* __restrict__ h1)
{
  __shared__ float wsl[256 * 8];
  __shared__ float rsum[256 * 9];
  __shared__ float rsq[256 * 9];
  const int c0 = blockIdx.x * 8;
  const int t = threadIdx.x;
#pragma unroll
  for (int j = 0; j < 8; ++j) wsl[t * 8 + j] = W[t * 128 + c0 + j];
  __syncthreads();
  float acc[8] = {0.f, 0.f, 0.f, 0.f, 0.f, 0.f, 0.f, 0.f};
  const float* grow = &g[t * 256];
#pragma unroll
  for (int k = 0; k < 256; k += 4) {
    float4 gv = *(const float4*)&grow[k];
#pragma unroll
    for (int j = 0; j < 8; ++j) {
      acc[j] += gv.x * wsl[(k + 0) * 8 + j] + gv.y * wsl[(k + 1) * 8 + j]
              + gv.z * wsl[(k + 2) * 8 + j] + gv.w * wsl[(k + 3) * 8 + j];
    }
  }
#pragma unroll
  for (int j = 0; j < 8; ++j) {
    acc[j] += bias[c0 + j];
    rsum[t * 9 + j] = acc[j];
    rsq[t * 9 + j] = acc[j] * acc[j];
  }
  __syncthreads();
  for (int s = 128; s > 0; s >>= 1) {
    if (t < s) {
#pragma unroll
      for (int j = 0; j < 8; ++j) {
        rsum[t * 9 + j] += rsum[(t + s) * 9 + j];
        rsq[t * 9 + j]  += rsq[(t + s) * 9 + j];
      }
    }
    __syncthreads();
  }
#pragma unroll
  for (int j = 0; j < 8; ++j) {
    float m = rsum[j] * (1.f / 256.f);
    float var = rsq[j] * (1.f / 256.f) - m * m;
    float o = gamma[c0 + j] * (acc[j] - m) * rsqrtf(var + 1e-5f) + beta[c0 + j];
    h1[t * 128 + c0 + j] = fmaxf(o, 0.f);
  }
}

// ---------------- head2: h2 = relu(bn2(h1 @ fc2_W + b2)); 8 blocks x 8 cols
__global__ __launch_bounds__(256) void head2_k(
    const float* __restrict__ h1, const float* __restrict__ W,
    const float* __restrict__ bias, const float* __restrict__ gamma,
    const float* __restrict__ beta, float* __restrict__ h2)
{
  __shared__ float wsl[128 * 8];
  __shared__ float rsum[256 * 9];
  __shared__ float rsq[256 * 9];
  const int c0 = blockIdx.x * 8;
  const int t = threadIdx.x;
  if (t < 128) {
#pragma unroll
    for (int j = 0; j < 8; ++j) wsl[t * 8 + j] = W[t * 64 + c0 + j];
  }
  __syncthreads();
  float acc[8] = {0.f, 0.f, 0.f, 0.f, 0.f, 0.f, 0.f, 0.f};
  const float* hrow = &h1[t * 128];
#pragma unroll
  for (int k = 0; k < 128; k += 4) {
    float4 gv = *(const float4*)&hrow[k];
#pragma unroll
    for (int j = 0; j < 8; ++j) {
      acc[j] += gv.x * wsl[(k + 0) * 8 + j] + gv.y * wsl[(k + 1) * 8 + j]
              + gv.z * wsl[(k + 2) * 8 + j] + gv.w * wsl[(k + 3) * 8 + j];
    }
  }
#pragma unroll
  for (int j = 0; j < 8; ++j) {
    acc[j] += bias[c0 + j];
    rsum[t * 9 + j] = acc[j];
    rsq[t * 9 + j] = acc[j] * acc[j];
  }
  __syncthreads();
  for (int s = 128; s > 0; s >>= 1) {
    if (t < s) {
#pragma unroll
      for (int j = 0; j < 8; ++j) {
        rsum[t * 9 + j] += rsum[(t + s) * 9 + j];
        rsq[t * 9 + j]  += rsq[(t + s) * 9 + j];
      }
    }
    __syncthreads();
  }
#pragma unroll
  for (int j = 0; j < 8; ++j) {
    float m = rsum[j] * (1.f / 256.f);
    float var = rsq[j] * (1.f / 256.f) - m * m;
    float o = gamma[c0 + j] * (acc[j] - m) * rsqrtf(var + 1e-5f) + beta[c0 + j];
    h2[t * 64 + c0 + j] = fmaxf(o, 0.f);
  }
}

// ---------------- out[nid] = sigmoid(dot(x0[nid][0:64], h2[graph]))
__global__ __launch_bounds__(256) void final_k(
    const float* __restrict__ x0, const float* __restrict__ g2,
    float* __restrict__ out, int total)
{
  int nid = blockIdx.x * 256 + threadIdx.x;
  if (nid >= total) return;
  int b = nid >> 9;
  const float* e = &x0[(size_t)nid * FDIM];   // first 64 cols = emb_item row
  const float* gg = &g2[(size_t)b * 64];
  float s = 0.f;
#pragma unroll
  for (int j = 0; j < 64; j += 4) {
    float4 a = *(const float4*)&e[j];
    float4 c = *(const float4*)&gg[j];
    s += a.x * c.x + a.y * c.y + a.z * c.z + a.w * c.w;
  }
  out[nid] = 1.f / (1.f + expf(-s));
}

// ---------------------------------------------------------------------------
extern "C" void kernel_launch(void* const* d_in, const int* in_sizes, int n_in,
                              void* d_out, int out_size, void* d_ws, size_t ws_size,
                              hipStream_t stream)
{
  const int*   item_id  = (const int*)  d_in[0];
  const int*   cat_id   = (const int*)  d_in[1];
  const int*   src_in   = (const int*)  d_in[2];
  const int*   dst_in   = (const int*)  d_in[3];
  const float* emb_item = (const float*)d_in[4];
  const float* emb_cat  = (const float*)d_in[5];
  const float* W1r = (const float*)d_in[6];
  const float* W1n = (const float*)d_in[7];
  const float* b1  = (const float*)d_in[8];
  const float* p1  = (const float*)d_in[9];
  const float* W2r = (const float*)d_in[10];
  const float* W2n = (const float*)d_in[11];
  const float* b2  = (const float*)d_in[12];
  const float* p2  = (const float*)d_in[13];
  const float* W3r = (const float*)d_in[14];
  const float* W3n = (const float*)d_in[15];
  const float* b3  = (const float*)d_in[16];
  const float* p3  = (const float*)d_in[17];
  const float* fc1_W = (const float*)d_in[18];
  const float* fc1_b = (const float*)d_in[19];
  const float* bn1_g = (const float*)d_in[20];
  const float* bn1_b = (const float*)d_in[21];
  const float* fc2_W = (const float*)d_in[22];
  const float* fc2_b = (const float*)d_in[23];
  const float* bn2_g = (const float*)d_in[24];
  const float* bn2_b = (const float*)d_in[25];
  float* out = (float*)d_out;

  const int TN = TOTAL_NODES;
  const int E  = E_TOTAL;
  const int k1 = 461, k2 = 415, k3 = 374;
  const int M1 = TN;              // 131072
  const int M2 = NUM_GRAPHS * k1; // 118016
  const int M3 = NUM_GRAPHS * k2; // 106240

  char* ws = (char*)d_ws;
  size_t off = 0;
  auto carve = [&](size_t bytes) { char* p = ws + off; off += align256(bytes); return p; };
  float*  bufA   = (float*) carve((size_t)TN * FDIM * 4);  // x0 (persists)
  float*  bufB   = (float*) carve((size_t)TN * FDIM * 4);  // agg1/x1, agg3/x3
  float*  bufC   = (float*) carve((size_t)TN * FDIM * 4);  // agg2/x2
  float*  score  = (float*) carve((size_t)TN * 4);
  int*    sel    = (int*)   carve((size_t)TN * 4);
  float*  gates  = (float*) carve((size_t)TN * 4);
  int*    srcw   = (int*)   carve((size_t)E * 4);
  int*    dstw   = (int*)   carve((size_t)E * 4);
  int*    counts = (int*)   carve((size_t)TN * 4);
  int*    offs   = (int*)   carve((size_t)TN * 4);
  int2*   slotp  = (int2*)  carve((size_t)E * 8);
  __bf16* wbuf   = (__bf16*)carve(6 * 2 * 16384 * 2);
  float*  g      = (float*) carve(256 * 256 * 4);
  float*  h1     = (float*) carve(256 * 128 * 4);
  float*  h2     = (float*) carve(256 * 64 * 4);
  float*  nrm    = (float*) carve(256);
  if (off > ws_size) return;

  dim3 b256(256);
  auto blocks = [](long long work, int bs) { return dim3((unsigned)((work + bs - 1) / bs)); };

  const __bf16* W1r_hl = wbuf + 0 * 2 * 16384;
  const __bf16* W1n_hl = wbuf + 1 * 2 * 16384;
  const __bf16* W2r_hl = wbuf + 2 * 2 * 16384;
  const __bf16* W2n_hl = wbuf + 3 * 2 * 16384;
  const __bf16* W3r_hl = wbuf + 4 * 2 * 16384;
  const __bf16* W3n_hl = wbuf + 5 * 2 * 16384;

  hipMemsetAsync(g, 0, 256 * 256 * 4, stream);
  wprep_k<<<dim3(64, 6), b256, 0, stream>>>(W1r, W1n, W2r, W2n, W3r, W3n, wbuf);
  pnorm3_k<<<dim3(1), dim3(128), 0, stream>>>(p1, p2, p3, nrm);
  gather_embed_k<<<blocks((long long)TN * 32, 256), b256, 0, stream>>>(
      item_id, cat_id, emb_item, emb_cat, bufA, TN);

  // ================= stage 1 (x0 = bufA dense) =================
  csr_build1_k<<<dim3(NUM_GRAPHS), dim3(512), 0, stream>>>(
      src_in, dst_in, srcw, dstw, slotp, counts, offs);
  gather_direct_k<<<blocks((long long)M1 * 32, 256), b256, 0, stream>>>(
      bufA, slotp, offs, counts, bufB, M1);
  conv_mfma_k<<<dim3(M1 / 128), b256, 0, stream>>>(
      bufA, nullptr, nullptr, W1r_hl, bufB, W1n_hl, b1, p1, nrm + 0, bufB, score, M1);
  topk_csr_k<<<dim3(NUM_GRAPHS), dim3(512), 0, stream>>>(
      score, NODES_PER_G, k1, sel, gates, srcw, dstw, slotp, counts, offs);
  readout_k<<<dim3(NUM_GRAPHS, 4), b256, 0, stream>>>(bufB, sel, gates, g, k1);

  // ================= stage 2 (x1 = bufB via sel/gates) =================
  gather_direct_k<<<blocks((long long)M2 * 32, 256), b256, 0, stream>>>(
      bufB, slotp, offs, counts, bufC, M2);
  conv_mfma_k<<<dim3(M2 / 128), b256, 0, stream>>>(
      bufB, sel, gates, W2r_hl, bufC, W2n_hl, b2, p2, nrm + 1, bufC, score, M2);
  topk_csr_k<<<dim3(NUM_GRAPHS), dim3(512), 0, stream>>>(
      score, k1, k2, sel, gates, srcw, dstw, slotp, counts, offs);
  readout_k<<<dim3(NUM_GRAPHS, 4), b256, 0, stream>>>(bufC, sel, gates, g, k2);

  // ================= stage 3 (x2 = bufC via sel/gates) =================
  gather_direct_k<<<blocks((long long)M3 * 32, 256), b256, 0, stream>>>(
      bufC, slotp, offs, counts, bufB, M3);
  conv_mfma_k<<<dim3(M3 / 128), b256, 0, stream>>>(
      bufC, sel, gates, W3r_hl, bufB, W3n_hl, b3, p3, nrm + 2, bufB, score, M3);
  topk_csr_k<<<dim3(NUM_GRAPHS), dim3(512), 0, stream>>>(
      score, k2, k3, sel, gates, nullptr, nullptr, nullptr, nullptr, nullptr);
  readout_k<<<dim3(NUM_GRAPHS, 4), b256, 0, stream>>>(bufB, sel, gates, g, k3);

  // ================= head (fused fc+bn+relu) =================
  head1_k<<<dim3(16), b256, 0, stream>>>(g, fc1_W, fc1_b, bn1_g, bn1_b, h1);
  head2_k<<<dim3(8), b256, 0, stream>>>(h1, fc2_W, fc2_b, bn2_g, bn2_b, h2);

  final_k<<<blocks(TN, 256), b256, 0, stream>>>(bufA, h2, out, TN);
}